// Round 3
// baseline (139.105 us; speedup 1.0000x reference)
//
#include <hip/hip_runtime.h>
#include <math.h>

#define THREADS 256
#define NWAVE 4
#define QB 64

__global__ void prep_kernel(const float* __restrict__ pred, const float* __restrict__ gt,
                            float4* __restrict__ p4, float4* __restrict__ g4, int total)
{
    int i = blockIdx.x * blockDim.x + threadIdx.x;
    if (i < 2 * total) {
        const float* src = (i < total) ? pred : gt;
        float4* dst = (i < total) ? p4 : g4;
        int k = (i < total) ? i : i - total;
        float x = src[3 * k + 0], y = src[3 * k + 1], z = src[3 * k + 2];
        dst[k] = make_float4(x, y, z, fmaf(x, x, fmaf(y, y, z * z)));
    }
}

// role 0: queries = gt,   targets = pred, weight 0.8  -> acc[0]
// role 1: queries = pred, targets = gt,   weight 0.2  -> acc[0]
// role 2: queries = pred, targets = pred, 4-NN uniform loss -> acc[1]
template<bool PRE>
__global__ __launch_bounds__(THREADS) void scan_kernel(
    const float* __restrict__ pred, const float* __restrict__ gt,
    const float4* __restrict__ p4, const float4* __restrict__ g4,
    const float* __restrict__ radius, float* __restrict__ acc,
    int B, int N, int chunksPerBatch)
{
    __shared__ float part[NWAVE][QB][4];

    const float FLT_INF = 3.4e38f;
    const float RADIUS = 0.07f;
    const float INV_H2 = 1.0f / (0.03f * 0.03f);
    const float EPSV = 1e-12f;

    int blocksPerRole = B * chunksPerBatch;
    int role  = blockIdx.x / blocksPerRole;
    int rem   = blockIdx.x % blocksPerRole;
    int b     = rem / chunksPerBatch;
    int chunk = rem % chunksPerBatch;

    int w  = threadIdx.x >> 6;
    int wu = __builtin_amdgcn_readfirstlane(w);   // provably wave-uniform wave id
    int l  = threadIdx.x & 63;
    int i  = chunk * QB + l;                      // query idx within batch

    const float* qsrc = (role == 0) ? gt : pred;
    const float* qb = qsrc + (size_t)b * N * 3;

    bool valid = (i < N);
    float qx = 0.f, qy = 0.f, qz = 0.f;
    if (valid) { qx = qb[i * 3 + 0]; qy = qb[i * 3 + 1]; qz = qb[i * 3 + 2]; }
    float na = fmaf(qx, qx, fmaf(qy, qy, qz * qz));

    int seg  = (N + NWAVE - 1) / NWAVE;
    int jbeg = wu * seg;
    int jend = min(jbeg + seg, N);

    if (role < 2) {
        float m0 = FLT_INF, m1 = FLT_INF, m2 = FLT_INF, m3 = FLT_INF;
        if (PRE) {
            const float4* __restrict__ ts = ((role == 1) ? g4 : p4) + (size_t)b * N;
            int j = jbeg;
            for (; j + 4 <= jend; j += 4) {
                float4 t0 = ts[j + 0], t1 = ts[j + 1], t2 = ts[j + 2], t3 = ts[j + 3];
                m0 = fminf(m0, fmaf(-2.f, fmaf(qx, t0.x, fmaf(qy, t0.y, qz * t0.z)), t0.w));
                m1 = fminf(m1, fmaf(-2.f, fmaf(qx, t1.x, fmaf(qy, t1.y, qz * t1.z)), t1.w));
                m2 = fminf(m2, fmaf(-2.f, fmaf(qx, t2.x, fmaf(qy, t2.y, qz * t2.z)), t2.w));
                m3 = fminf(m3, fmaf(-2.f, fmaf(qx, t3.x, fmaf(qy, t3.y, qz * t3.z)), t3.w));
            }
            for (; j < jend; ++j) {
                float4 t = ts[j];
                m0 = fminf(m0, fmaf(-2.f, fmaf(qx, t.x, fmaf(qy, t.y, qz * t.z)), t.w));
            }
        } else {
            const float* __restrict__ ts = ((role == 1) ? gt : pred) + (size_t)b * N * 3;
            int j = jbeg;
            for (; j + 2 <= jend; j += 2) {
                float ax = ts[3*j+0], ay = ts[3*j+1], az = ts[3*j+2];
                float bx = ts[3*j+3], by = ts[3*j+4], bz = ts[3*j+5];
                float d0x = qx - ax, d0y = qy - ay, d0z = qz - az;
                float d1x = qx - bx, d1y = qy - by, d1z = qz - bz;
                m0 = fminf(m0, fmaf(d0x, d0x, fmaf(d0y, d0y, d0z * d0z)));
                m1 = fminf(m1, fmaf(d1x, d1x, fmaf(d1y, d1y, d1z * d1z)));
            }
            for (; j < jend; ++j) {
                float ax = ts[3*j+0], ay = ts[3*j+1], az = ts[3*j+2];
                float dx = qx - ax, dy = qy - ay, dz = qz - az;
                m0 = fminf(m0, fmaf(dx, dx, fmaf(dy, dy, dz * dz)));
            }
        }
        part[w][l][0] = fminf(fminf(m0, m1), fminf(m2, m3));
    } else {
        float b0 = FLT_INF, b1 = FLT_INF, b2 = FLT_INF, b3 = FLT_INF;
        if (PRE) {
            const float4* __restrict__ ts = p4 + (size_t)b * N;
            for (int j = jbeg; j < jend; ++j) {
                float4 t = ts[j];
                float c = fmaf(-2.f, fmaf(qx, t.x, fmaf(qy, t.y, qz * t.z)), t.w);
                c = (j == i) ? FLT_INF : c;       // exclude self
                float m = c, n;                   // branchless sorted insert
                n = fminf(b0, m); m = fmaxf(b0, m); b0 = n;
                n = fminf(b1, m); m = fmaxf(b1, m); b1 = n;
                n = fminf(b2, m); m = fmaxf(b2, m); b2 = n;
                b3 = fminf(b3, m);
            }
        } else {
            const float* __restrict__ ts = pred + (size_t)b * N * 3;
            for (int j = jbeg; j < jend; ++j) {
                float ax = ts[3*j+0], ay = ts[3*j+1], az = ts[3*j+2];
                float dx = qx - ax, dy = qy - ay, dz = qz - az;
                float c = fmaf(dx, dx, fmaf(dy, dy, dz * dz));
                c = (j == i) ? FLT_INF : c;
                float m = c, n;
                n = fminf(b0, m); m = fmaxf(b0, m); b0 = n;
                n = fminf(b1, m); m = fmaxf(b1, m); b1 = n;
                n = fminf(b2, m); m = fmaxf(b2, m); b2 = n;
                b3 = fminf(b3, m);
            }
        }
        part[w][l][0] = b0; part[w][l][1] = b1;
        part[w][l][2] = b2; part[w][l][3] = b3;
    }
    __syncthreads();

    // wave 0 merges partials and reduces
    float contrib = 0.f;
    if (threadIdx.x < QB && valid) {
        float base = PRE ? na : 0.f;              // PRE stores nb-2dot; !PRE stores d2
        float inv_r = 1.0f / radius[b];
        if (role < 2) {
            float best = fminf(fminf(part[0][l][0], part[1][l][0]),
                               fminf(part[2][l][0], part[3][l][0]));
            float wgt = (role == 0) ? 0.8f : 0.2f;
            contrib = wgt * inv_r * (base + best);
        } else {
            float s0 = FLT_INF, s1 = FLT_INF, s2 = FLT_INF, s3 = FLT_INF;
            #pragma unroll
            for (int ww = 0; ww < NWAVE; ++ww) {
                #pragma unroll
                for (int k = 0; k < 4; ++k) {
                    float m = part[ww][l][k], n;
                    n = fminf(s0, m); m = fmaxf(s0, m); s0 = n;
                    n = fminf(s1, m); m = fmaxf(s1, m); s1 = n;
                    n = fminf(s2, m); m = fmaxf(s2, m); s2 = n;
                    s3 = fminf(s3, m);
                }
            }
            float ss[4] = {s0, s1, s2, s3};
            float s = 0.f;
            #pragma unroll
            for (int k = 0; k < 4; ++k) {
                float d2 = fmaxf(base + ss[k], EPSV);
                float dist = sqrtf(d2);
                float wgt = __expf(-d2 * INV_H2);
                s += (RADIUS - dist) * wgt;
            }
            contrib = s;
        }
    }
    if (threadIdx.x < 64) {
        #pragma unroll
        for (int off = 32; off > 0; off >>= 1) contrib += __shfl_down(contrib, off, 64);
        if (threadIdx.x == 0) atomicAdd(&acc[role < 2 ? 0 : 1], contrib);
    }
}

__global__ void upsample_final_kernel(const float* __restrict__ acc,
                                      float* __restrict__ out,
                                      float invCd, float invUni)
{
    out[0] = fmaf(acc[0], invCd, 0.1f * acc[1] * invUni);
}

extern "C" void kernel_launch(void* const* d_in, const int* in_sizes, int n_in,
                              void* d_out, int out_size, void* d_ws, size_t ws_size,
                              hipStream_t stream) {
    const float* pred   = (const float*)d_in[0];
    const float* gt     = (const float*)d_in[1];
    const float* radius = (const float*)d_in[2];
    float* out = (float*)d_out;

    int B = in_sizes[2];
    int N = in_sizes[0] / (3 * B);
    int total = B * N;

    float* acc = (float*)d_ws;
    float4* p4 = (float4*)((char*)d_ws + 16);
    float4* g4 = p4 + total;
    size_t need = 16 + 2 * (size_t)total * sizeof(float4);
    bool pre = (ws_size >= need);

    hipMemsetAsync(acc, 0, 2 * sizeof(float), stream);

    int chunksPerBatch = (N + QB - 1) / QB;
    int blocks = 3 * B * chunksPerBatch;

    if (pre) {
        int pblocks = (2 * total + 255) / 256;
        prep_kernel<<<pblocks, 256, 0, stream>>>(pred, gt, p4, g4, total);
        scan_kernel<true><<<blocks, THREADS, 0, stream>>>(pred, gt, p4, g4, radius, acc,
                                                          B, N, chunksPerBatch);
    } else {
        scan_kernel<false><<<blocks, THREADS, 0, stream>>>(pred, gt, p4, g4, radius, acc,
                                                           B, N, chunksPerBatch);
    }

    float invCd  = 1.0f / ((float)B * (float)N);
    float invUni = 1.0f / ((float)B * (float)N * 4.0f);
    upsample_final_kernel<<<1, 1, 0, stream>>>(acc, out, invCd, invUni);
}

// Round 4
// 115.049 us; speedup vs baseline: 1.2091x; 1.2091x over previous
//
#include <hip/hip_runtime.h>
#include <math.h>

#define THREADS 256
#define NWAVE 4
#define QB 128            // queries per block (2 per lane)
#define TILE 2048         // targets staged in LDS per tile

typedef float v2f __attribute__((ext_vector_type(2)));

__device__ __forceinline__ v2f vfma2(v2f a, v2f b, v2f c) {
#if __has_builtin(__builtin_elementwise_fma)
    return __builtin_elementwise_fma(a, b, c);
#else
    v2f r; r.x = fmaf(a.x, b.x, c.x); r.y = fmaf(a.y, b.y, c.y); return r;
#endif
}
__device__ __forceinline__ v2f vmin2(v2f a, v2f b) {
#if __has_builtin(__builtin_elementwise_min)
    return __builtin_elementwise_min(a, b);
#else
    v2f r; r.x = fminf(a.x, b.x); r.y = fminf(a.y, b.y); return r;
#endif
}
__device__ __forceinline__ v2f vmax2(v2f a, v2f b) {
#if __has_builtin(__builtin_elementwise_max)
    return __builtin_elementwise_max(a, b);
#else
    v2f r; r.x = fmaxf(a.x, b.x); r.y = fmaxf(a.y, b.y); return r;
#endif
}

// c = nb - 2*dot(q,t), two queries packed
__device__ __forceinline__ v2f pdist(v2f QX, v2f QY, v2f QZ, float4 t) {
    v2f tx = {t.x, t.x}, ty = {t.y, t.y}, tz = {t.z, t.z}, tw = {t.w, t.w};
    v2f d = QZ * tz;
    d = vfma2(QY, ty, d);
    d = vfma2(QX, tx, d);
    v2f m2 = {-2.f, -2.f};
    return vfma2(m2, d, tw);
}

// branchless sorted insert of C into B0<=..<=B4 (per v2f slot)
#define INS5(C) do { v2f m_ = (C), n_;                         \
    n_ = vmin2(B0, m_); m_ = vmax2(B0, m_); B0 = n_;           \
    n_ = vmin2(B1, m_); m_ = vmax2(B1, m_); B1 = n_;           \
    n_ = vmin2(B2, m_); m_ = vmax2(B2, m_); B2 = n_;           \
    n_ = vmin2(B3, m_); m_ = vmax2(B3, m_); B3 = n_;           \
    B4 = vmin2(B4, m_); } while (0)

// role 0: queries = gt,   targets = pred, weight 0.8  -> acc[0]
// role 1: queries = pred, targets = gt,   weight 0.2  -> acc[0]
// role 2: queries = pred, targets = pred, top-5 (drop self=min) uniform -> acc[1]
__global__ __launch_bounds__(THREADS) void scan_kernel(
    const float* __restrict__ pred, const float* __restrict__ gt,
    const float* __restrict__ radius, float* __restrict__ acc,
    int B, int N, int chunksPerBatch)
{
    __shared__ float4 tgt[TILE];
    __shared__ float part[NWAVE][QB][5];
    __shared__ float naArr[QB];
    __shared__ float red[THREADS / 64];

    const float FLT_INF = 3.4e38f;
    const float RADIUS = 0.07f;
    const float INV_H2 = 1.0f / (0.03f * 0.03f);
    const float EPSV = 1e-12f;

    int blocksPerRole = B * chunksPerBatch;
    int role  = blockIdx.x / blocksPerRole;
    int rem   = blockIdx.x % blocksPerRole;
    int b     = rem / chunksPerBatch;
    int chunk = rem % chunksPerBatch;

    int w = threadIdx.x >> 6;
    int l = threadIdx.x & 63;
    int qi0 = chunk * QB + l;         // query slot .x
    int qi1 = qi0 + 64;               // query slot .y

    const float* qsrc = (role == 0) ? gt : pred;
    const float* qb = qsrc + (size_t)b * N * 3;
    const float* tb = ((role == 1) ? gt : pred) + (size_t)b * N * 3;

    v2f QX = {0.f, 0.f}, QY = {0.f, 0.f}, QZ = {0.f, 0.f};
    if (qi0 < N) { QX.x = qb[qi0*3]; QY.x = qb[qi0*3+1]; QZ.x = qb[qi0*3+2]; }
    if (qi1 < N) { QX.y = qb[qi1*3]; QY.y = qb[qi1*3+1]; QZ.y = qb[qi1*3+2]; }
    v2f NA = vfma2(QX, QX, vfma2(QY, QY, QZ * QZ));
    if (w == 0) { naArr[l] = NA.x; naArr[l + 64] = NA.y; }

    v2f M0 = {FLT_INF, FLT_INF}, M1 = M0, M2 = M0, M3 = M0;     // chamfer
    v2f B0 = M0, B1 = M0, B2 = M0, B3 = M0, B4 = M0;            // knn top-5

    for (int t0 = 0; t0 < N; t0 += TILE) {
        int cnt = min(TILE, N - t0);
        for (int k = threadIdx.x; k < cnt; k += THREADS) {
            float x = tb[(size_t)(t0 + k) * 3 + 0];
            float y = tb[(size_t)(t0 + k) * 3 + 1];
            float z = tb[(size_t)(t0 + k) * 3 + 2];
            tgt[k] = make_float4(x, y, z, fmaf(x, x, fmaf(y, y, z * z)));
        }
        __syncthreads();

        int segsz = (cnt + NWAVE - 1) / NWAVE;
        int jb = w * segsz;
        int je = min(jb + segsz, cnt);

        if (role < 2) {
            int j = jb;
            for (; j + 4 <= je; j += 4) {
                float4 t0v = tgt[j], t1v = tgt[j+1], t2v = tgt[j+2], t3v = tgt[j+3];
                M0 = vmin2(M0, pdist(QX, QY, QZ, t0v));
                M1 = vmin2(M1, pdist(QX, QY, QZ, t1v));
                M2 = vmin2(M2, pdist(QX, QY, QZ, t2v));
                M3 = vmin2(M3, pdist(QX, QY, QZ, t3v));
            }
            for (; j < je; ++j) M0 = vmin2(M0, pdist(QX, QY, QZ, tgt[j]));
        } else {
            int j = jb;
            for (; j + 2 <= je; j += 2) {
                float4 t0v = tgt[j], t1v = tgt[j+1];
                v2f c0 = pdist(QX, QY, QZ, t0v);
                v2f c1 = pdist(QX, QY, QZ, t1v);
                INS5(c0);
                INS5(c1);
            }
            for (; j < je; ++j) INS5(pdist(QX, QY, QZ, tgt[j]));
        }
        __syncthreads();
    }

    if (role < 2) {
        v2f M = vmin2(vmin2(M0, M1), vmin2(M2, M3));
        part[w][l][0] = M.x;
        part[w][l + 64][0] = M.y;
    } else {
        part[w][l][0] = B0.x; part[w][l][1] = B1.x; part[w][l][2] = B2.x;
        part[w][l][3] = B3.x; part[w][l][4] = B4.x;
        part[w][l+64][0] = B0.y; part[w][l+64][1] = B1.y; part[w][l+64][2] = B2.y;
        part[w][l+64][3] = B3.y; part[w][l+64][4] = B4.y;
    }
    __syncthreads();

    // merge partials: thread t handles query chunk*QB + t
    float contrib = 0.f;
    int t = threadIdx.x;
    if (t < QB) {
        int qi = chunk * QB + t;
        if (qi < N) {
            float inv_r = 1.0f / radius[b];
            float na = naArr[t];
            if (role < 2) {
                float best = fminf(fminf(part[0][t][0], part[1][t][0]),
                                   fminf(part[2][t][0], part[3][t][0]));
                float wgt = (role == 0) ? 0.8f : 0.2f;
                contrib = wgt * inv_r * (na + best);
            } else {
                float s0 = FLT_INF, s1 = FLT_INF, s2 = FLT_INF, s3 = FLT_INF, s4 = FLT_INF;
                #pragma unroll
                for (int ww = 0; ww < NWAVE; ++ww) {
                    #pragma unroll
                    for (int k = 0; k < 5; ++k) {
                        float m = part[ww][t][k], n;
                        n = fminf(s0, m); m = fmaxf(s0, m); s0 = n;
                        n = fminf(s1, m); m = fmaxf(s1, m); s1 = n;
                        n = fminf(s2, m); m = fmaxf(s2, m); s2 = n;
                        n = fminf(s3, m); m = fmaxf(s3, m); s3 = n;
                        s4 = fminf(s4, m);
                    }
                }
                // s0 is self (global min) -> dropped; ranks 1..4 contribute
                float ss[4] = {s1, s2, s3, s4};
                float s = 0.f;
                #pragma unroll
                for (int k = 0; k < 4; ++k) {
                    float d2 = fmaxf(na + ss[k], EPSV);
                    float dist = sqrtf(d2);
                    float wgt = __expf(-d2 * INV_H2);
                    s += (RADIUS - dist) * wgt;
                }
                contrib = s;
            }
        }
    }
    #pragma unroll
    for (int off = 32; off > 0; off >>= 1) contrib += __shfl_down(contrib, off, 64);
    if (l == 0) red[w] = contrib;
    __syncthreads();
    if (threadIdx.x == 0) {
        atomicAdd(&acc[role < 2 ? 0 : 1], red[0] + red[1] + red[2] + red[3]);
    }
}

__global__ void upsample_final_kernel(const float* __restrict__ acc,
                                      float* __restrict__ out,
                                      float invCd, float invUni)
{
    out[0] = fmaf(acc[0], invCd, 0.1f * acc[1] * invUni);
}

extern "C" void kernel_launch(void* const* d_in, const int* in_sizes, int n_in,
                              void* d_out, int out_size, void* d_ws, size_t ws_size,
                              hipStream_t stream) {
    const float* pred   = (const float*)d_in[0];
    const float* gt     = (const float*)d_in[1];
    const float* radius = (const float*)d_in[2];
    float* out = (float*)d_out;
    float* acc = (float*)d_ws;

    int B = in_sizes[2];
    int N = in_sizes[0] / (3 * B);

    hipMemsetAsync(acc, 0, 2 * sizeof(float), stream);

    int chunksPerBatch = (N + QB - 1) / QB;
    int blocks = 3 * B * chunksPerBatch;
    scan_kernel<<<blocks, THREADS, 0, stream>>>(pred, gt, radius, acc,
                                                B, N, chunksPerBatch);

    float invCd  = 1.0f / ((float)B * (float)N);
    float invUni = 1.0f / ((float)B * (float)N * 4.0f);
    upsample_final_kernel<<<1, 1, 0, stream>>>(acc, out, invCd, invUni);
}